// Round 5
// baseline (612.290 us; speedup 1.0000x reference)
//
#include <hip/hip_runtime.h>
#include <hip/hip_fp16.h>
#include <stdint.h>

#define NV 100000
#define NE 3200000
#define NF 128
#define CAP 96        // ELL row capacity (in-degree Poisson(32); P(>96) ~ 0)
#define NB 782        // buckets = ceil(NV/128), 128 nodes per bucket
#define NSH 8         // shards (by blockIdx&7 ~ XCD)
#define SUBCAP 768    // per-(shard,bucket) capacity: mean 512, +11 sigma

typedef unsigned int u32;

// ---------------- workspace layout (bytes) ----------------
// bkt  : NSH*NB*SUBCAP uint2   @ 0           (38,438,912)  [xwh fp16 aliases @0 later]
// ell  : NV*CAP uint2          @ 38438912    (76,800,000)
// dinv : NV f32                @ 115238912   (400,000)
// bcnt : NSH*NB u32            @ 115638912   (25,024)
// flag : u32                   @ 115664000
// cnt  : NV u32                @ 115664064   (400,000)
// total ~ 116.1 MB
#define OFF_BKT   0ull
#define OFF_ELL   38438912ull
#define OFF_DINV  115238912ull
#define OFF_BCNT  115638912ull
#define OFF_FLAG  115664000ull
#define OFF_CNT   115664064ull

// ---------------- edge-index dtype detection ----------------
// int64 indices < 100000 => every odd u32 word is 0.
__global__ void k_detect(const u32* __restrict__ ei_raw, u32* __restrict__ flag) {
    int t = threadIdx.x;  // 64 threads
    unsigned long long ball = __ballot(ei_raw[2 * t + 1] == 0u);
    if (t == 0) *flag = (__popcll(ball) > 32) ? 1u : 0u;
}

__device__ inline void load_edge(const void* ei, u32 is64, int e, int& s, int& d) {
    if (is64) {
        const long long* p = (const long long*)ei;
        s = (int)p[e];
        d = (int)p[NE + e];
    } else {
        const int* p = (const int*)ei;
        s = p[e];
        d = p[NE + e];
    }
}

// ---------------- build pass 0: counters ----------------
__global__ __launch_bounds__(256) void k_init(u32* bcnt) {
    int i = blockIdx.x * 256 + threadIdx.x;
    if (i < NB * NSH) bcnt[i] = 0u;
}

// ---------------- build pass 1: bin edges by dst-range, XCD-sharded ----------------
// layout [shard][bucket]: each counter/tail line touched by ONE shard (≈ one XCD)
// record: {w_bits, src | (dst&127)<<17}
__global__ __launch_bounds__(256) void k_binscatter(const void* __restrict__ ei,
                                                    const float* __restrict__ w,
                                                    u32* __restrict__ bcnt,
                                                    uint2* __restrict__ bkt,
                                                    const u32* __restrict__ flag) {
    int e = blockIdx.x * 256 + threadIdx.x;
    if (e >= NE) return;
    u32 is64 = *flag;
    int s, d;
    load_edge(ei, is64, e, s, d);
    int bucket = d >> 7;
    int shard = blockIdx.x & (NSH - 1);     // ~XCD-local under round-robin dispatch
    int sb = shard * NB + bucket;           // [shard][bucket]: shard-private lines
    u32 pos = atomicAdd(&bcnt[sb], 1u);
    if (pos < SUBCAP)
        bkt[(size_t)sb * SUBCAP + pos] =
            make_uint2(__float_as_uint(w[e]), (u32)s | ((u32)(d & 127) << 17));
}

// ---------------- build pass 2: bucket lists -> ELL rows + dinv + cnt ----------------
__global__ __launch_bounds__(256) void k_build(const uint2* __restrict__ bkt,
                                               const u32* __restrict__ bcnt,
                                               uint2* __restrict__ ell,
                                               float* __restrict__ dinv,
                                               u32* __restrict__ cnt) {
    __shared__ u32 lcnt[128];
    __shared__ float lws[128];
    int bucket = blockIdx.x;
    int tid = threadIdx.x;
    if (tid < 128) { lcnt[tid] = 0u; lws[tid] = 0.f; }
    __syncthreads();
    int node0 = bucket << 7;
#pragma unroll 1
    for (int sh = 0; sh < NSH; ++sh) {
        int sb = sh * NB + bucket;
        u32 n = min(bcnt[sb], (u32)SUBCAP);
        const uint2* lst = bkt + (size_t)sb * SUBCAP;
        for (u32 i = tid; i < n; i += 256) {
            uint2 rec = lst[i];
            u32 src = rec.y & 0x1FFFFu;
            u32 dlo = (rec.y >> 17) & 127u;
            float wv = __uint_as_float(rec.x);
            u32 pos = atomicAdd(&lcnt[dlo], 1u);
            atomicAdd(&lws[dlo], wv);
            if (pos < CAP)
                ell[(size_t)(node0 + dlo) * CAP + pos] = make_uint2(rec.x, src);
        }
    }
    __syncthreads();
    if (tid < 128) {
        int node = node0 + tid;
        if (node < NV) {
            dinv[node] = rsqrtf(1.0f + lws[tid]);
            cnt[node] = min(lcnt[tid], (u32)CAP);
        }
    }
}

// ---------------- GEMM: Y[NV x 128] = dinv[row] * (X @ W), fp16 output ----------------
__device__ inline uint4 pack8h(float4 a, float4 b) {
    __half2 h0 = __float22half2_rn(make_float2(a.x, a.y));
    __half2 h1 = __float22half2_rn(make_float2(a.z, a.w));
    __half2 h2 = __float22half2_rn(make_float2(b.x, b.y));
    __half2 h3 = __float22half2_rn(make_float2(b.z, b.w));
    uint4 r;
    r.x = *(u32*)&h0; r.y = *(u32*)&h1; r.z = *(u32*)&h2; r.w = *(u32*)&h3;
    return r;
}

__device__ inline float4 scale4(float4 a, float s) {
    return make_float4(a.x * s, a.y * s, a.z * s, a.w * s);
}

__global__ __launch_bounds__(256) void k_gemm(const float* __restrict__ X,
                                              const float* __restrict__ Wm,
                                              const float* __restrict__ dinv,
                                              __half* __restrict__ Y) {
    __shared__ float Ws[64 * 128];   // 32 KB (half of W at a time)
    __shared__ float Xs[32 * 132];   // padded stride to dodge bank conflicts
    int tid = threadIdx.x;
    int row0 = blockIdx.x * 32;

    const float4* Xv = (const float4*)(X + (size_t)row0 * NF);
#pragma unroll
    for (int i = 0; i < 4; ++i) {
        int idx = tid + i * 256;
        int r = idx >> 5, c4 = idx & 31;
        *((float4*)(Xs + r * 132) + c4) = Xv[idx];
    }

    int cg = tid & 15, rg = tid >> 4;
    int c0 = cg * 8, r0 = rg * 2;
    float4 a00 = {0, 0, 0, 0}, a01 = {0, 0, 0, 0}, a10 = {0, 0, 0, 0}, a11 = {0, 0, 0, 0};

    for (int half_ = 0; half_ < 2; ++half_) {
        const float4* Wv = (const float4*)(Wm + half_ * 64 * NF);
        __syncthreads();
#pragma unroll
        for (int i = 0; i < 8; ++i) ((float4*)Ws)[tid + i * 256] = Wv[tid + i * 256];
        __syncthreads();
        const float* xr0 = Xs + r0 * 132 + half_ * 64;
        const float* xr1 = xr0 + 132;
#pragma unroll 8
        for (int k = 0; k < 64; ++k) {
            float x0 = xr0[k], x1 = xr1[k];
            float4 w0 = *(const float4*)&Ws[k * 128 + c0];
            float4 w1 = *(const float4*)&Ws[k * 128 + c0 + 4];
            a00.x = fmaf(x0, w0.x, a00.x); a00.y = fmaf(x0, w0.y, a00.y);
            a00.z = fmaf(x0, w0.z, a00.z); a00.w = fmaf(x0, w0.w, a00.w);
            a01.x = fmaf(x0, w1.x, a01.x); a01.y = fmaf(x0, w1.y, a01.y);
            a01.z = fmaf(x0, w1.z, a01.z); a01.w = fmaf(x0, w1.w, a01.w);
            a10.x = fmaf(x1, w0.x, a10.x); a10.y = fmaf(x1, w0.y, a10.y);
            a10.z = fmaf(x1, w0.z, a10.z); a10.w = fmaf(x1, w0.w, a10.w);
            a11.x = fmaf(x1, w1.x, a11.x); a11.y = fmaf(x1, w1.y, a11.y);
            a11.z = fmaf(x1, w1.z, a11.z); a11.w = fmaf(x1, w1.w, a11.w);
        }
    }

    float d0 = dinv[row0 + r0], d1 = dinv[row0 + r0 + 1];
    __half* yr0 = Y + (size_t)(row0 + r0) * NF + c0;
    *(uint4*)yr0 = pack8h(scale4(a00, d0), scale4(a01, d0));
    __half* yr1 = yr0 + NF;
    *(uint4*)yr1 = pack8h(scale4(a10, d1), scale4(a11, d1));
}

// ---------------- aggregation (1 wave per node), fp16 gathers, fused ReLU+LN ----------------
// out[d] = dinv[d] * (xw'[d] + sum_e w_e * xw'[src_e]) + bias,  xw' = dinv*(X@W)
template <int LN>
__global__ __launch_bounds__(256) void k_agg(const __half* __restrict__ xwh,
                                             const uint2* __restrict__ ell,
                                             const u32* __restrict__ cnt,
                                             const float* __restrict__ dinv,
                                             const float* __restrict__ bias,
                                             const float* __restrict__ gamma,
                                             const float* __restrict__ beta,
                                             float* __restrict__ out) {
    int node = blockIdx.x * 4 + (threadIdx.x >> 6);
    int lane = threadIdx.x & 63;
    const u32* xwu = (const u32*)xwh;   // one u32 = 2 fp16 features per lane

    float di = dinv[node];
    u32 sv = xwu[(size_t)node * (NF / 2) + lane];
    float2 xv = __half22float2(*(const __half2*)&sv);
    float ax = xv.x, ay = xv.y;         // self term: xw'[node] (has dinv already)

    const uint2* row = ell + (size_t)node * CAP;
    u32 c = min(cnt[node], (u32)CAP);
    u32 p = 0;
    for (; p + 4 <= c; p += 4) {
        uint2 e0 = row[p], e1 = row[p + 1], e2 = row[p + 2], e3 = row[p + 3];
        u32 s0 = __builtin_amdgcn_readfirstlane(e0.y);
        u32 s1 = __builtin_amdgcn_readfirstlane(e1.y);
        u32 s2 = __builtin_amdgcn_readfirstlane(e2.y);
        u32 s3 = __builtin_amdgcn_readfirstlane(e3.y);
        u32 v0 = xwu[(size_t)s0 * (NF / 2) + lane];
        u32 v1 = xwu[(size_t)s1 * (NF / 2) + lane];
        u32 v2 = xwu[(size_t)s2 * (NF / 2) + lane];
        u32 v3 = xwu[(size_t)s3 * (NF / 2) + lane];
        float c0 = __uint_as_float(e0.x), c1 = __uint_as_float(e1.x);
        float c2 = __uint_as_float(e2.x), c3 = __uint_as_float(e3.x);
        float2 f0 = __half22float2(*(const __half2*)&v0);
        float2 f1 = __half22float2(*(const __half2*)&v1);
        float2 f2 = __half22float2(*(const __half2*)&v2);
        float2 f3 = __half22float2(*(const __half2*)&v3);
        ax = fmaf(c0, f0.x, ax); ay = fmaf(c0, f0.y, ay);
        ax = fmaf(c1, f1.x, ax); ay = fmaf(c1, f1.y, ay);
        ax = fmaf(c2, f2.x, ax); ay = fmaf(c2, f2.y, ay);
        ax = fmaf(c3, f3.x, ax); ay = fmaf(c3, f3.y, ay);
    }
    for (; p < c; ++p) {
        uint2 e0 = row[p];
        u32 s0 = __builtin_amdgcn_readfirstlane(e0.y);
        u32 v0 = xwu[(size_t)s0 * (NF / 2) + lane];
        float2 f0 = __half22float2(*(const __half2*)&v0);
        float cc = __uint_as_float(e0.x);
        ax = fmaf(cc, f0.x, ax); ay = fmaf(cc, f0.y, ay);
    }
    ax = fmaf(ax, di, bias[2 * lane]);
    ay = fmaf(ay, di, bias[2 * lane + 1]);
    if (LN) {
        ax = fmaxf(ax, 0.f); ay = fmaxf(ay, 0.f);
        float s1 = ax + ay, s2 = ax * ax + ay * ay;
#pragma unroll
        for (int o = 32; o > 0; o >>= 1) {
            s1 += __shfl_xor(s1, o);
            s2 += __shfl_xor(s2, o);
        }
        float mu = s1 * (1.f / 128.f);
        float var = fmaf(-mu, mu, s2 * (1.f / 128.f));
        float rstd = rsqrtf(var + 1e-5f);
        ax = fmaf((ax - mu) * rstd, gamma[2 * lane], beta[2 * lane]);
        ay = fmaf((ay - mu) * rstd, gamma[2 * lane + 1], beta[2 * lane + 1]);
    }
    ((float2*)(out + (size_t)node * NF))[lane] = make_float2(ax, ay);
}

// ---------------- launch ----------------
extern "C" void kernel_launch(void* const* d_in, const int* in_sizes, int n_in,
                              void* d_out, int out_size, void* d_ws, size_t ws_size,
                              hipStream_t stream) {
    const float* x  = (const float*)d_in[0];
    const float* ew = (const float*)d_in[1];
    const float* W1 = (const float*)d_in[2];
    const float* b1 = (const float*)d_in[3];
    const float* g1 = (const float*)d_in[4];
    const float* be1 = (const float*)d_in[5];
    const float* W2 = (const float*)d_in[6];
    const float* b2 = (const float*)d_in[7];
    const void*  ei = d_in[8];

    char* ws = (char*)d_ws;
    uint2*  bkt  = (uint2*)(ws + OFF_BKT);
    uint2*  ell  = (uint2*)(ws + OFF_ELL);
    float*  dinv = (float*)(ws + OFF_DINV);
    u32*    bcnt = (u32*)(ws + OFF_BCNT);
    u32*    flag = (u32*)(ws + OFF_FLAG);
    u32*    cnt  = (u32*)(ws + OFF_CNT);
    __half* xwh  = (__half*)(ws + OFF_BKT);   // aliases bucket region (dead after k_build)
    float*  out  = (float*)d_out;
    float*  h    = (float*)d_out;             // layer-1 activations live in d_out

    const int gE = (NE + 255) / 256;          // 12500
    const int gN4 = NV / 4;                   // 25000

    k_detect<<<1, 64, 0, stream>>>((const u32*)ei, flag);
    k_init<<<(NB * NSH + 255) / 256, 256, 0, stream>>>(bcnt);
    k_binscatter<<<gE, 256, 0, stream>>>(ei, ew, bcnt, bkt, flag);
    k_build<<<NB, 256, 0, stream>>>(bkt, bcnt, ell, dinv, cnt);

    k_gemm<<<NV / 32, 256, 0, stream>>>(x, W1, dinv, xwh);
    k_agg<1><<<gN4, 256, 0, stream>>>(xwh, ell, cnt, dinv, b1, g1, be1, h);
    k_gemm<<<NV / 32, 256, 0, stream>>>(h, W2, dinv, xwh);
    k_agg<0><<<gN4, 256, 0, stream>>>(xwh, ell, cnt, dinv, b2, nullptr, nullptr, out);
}

// Round 6
// 555.682 us; speedup vs baseline: 1.1019x; 1.1019x over previous
//
#include <hip/hip_runtime.h>
#include <hip/hip_fp16.h>
#include <stdint.h>

#define NV 100000
#define NE 3200000
#define NF 128
#define CAP 96        // ELL row capacity (in-degree Poisson(32); P(>96) ~ 0)
#define NB 782        // buckets = ceil(NV/128), 128 nodes per bucket
#define NSH 32        // shards (by blockIdx&31): per-counter chain ~128
#define SUBCAP 224    // per-(shard,bucket) capacity: mean 128, +8.5 sigma
#define CPAD 16       // counter padding: 16 u32 = 64B -> one counter per cache line

typedef unsigned int u32;

// ---------------- workspace layout (bytes) ----------------
// bkt  : NSH*NB*SUBCAP uint2    @ 0            (44,845,056)  [xwh fp16 aliases @0 later]
// ell  : NV*CAP uint2           @ 44845056     (76,800,000)
// dinv : NV f32                 @ 121645056    (400,000)
// bcnt : NSH*NB*CPAD u32        @ 122045056    (1,601,536)   (padded: 1 counter / 64B line)
// flag : u32                    @ 123646592
// cnt  : NV u32                 @ 123646656    (400,000)
// total ~ 124.0 MB
#define OFF_BKT   0ull
#define OFF_ELL   44845056ull
#define OFF_DINV  121645056ull
#define OFF_BCNT  122045056ull
#define OFF_FLAG  123646592ull
#define OFF_CNT   123646656ull

// ---------------- edge-index dtype detection ----------------
// int64 indices < 100000 => every odd u32 word is 0.
__global__ void k_detect(const u32* __restrict__ ei_raw, u32* __restrict__ flag) {
    int t = threadIdx.x;  // 64 threads
    unsigned long long ball = __ballot(ei_raw[2 * t + 1] == 0u);
    if (t == 0) *flag = (__popcll(ball) > 32) ? 1u : 0u;
}

__device__ inline void load_edge(const void* ei, u32 is64, int e, int& s, int& d) {
    if (is64) {
        const long long* p = (const long long*)ei;
        s = (int)p[e];
        d = (int)p[NE + e];
    } else {
        const int* p = (const int*)ei;
        s = p[e];
        d = p[NE + e];
    }
}

// ---------------- build pass 0: counters ----------------
__global__ __launch_bounds__(256) void k_init(u32* bcnt) {
    int i = blockIdx.x * 256 + threadIdx.x;
    if (i < NB * NSH) bcnt[(size_t)i * CPAD] = 0u;
}

// ---------------- build pass 1: bin edges by dst-range, sharded, padded counters ----------------
// record: {w_bits, src | (dst&127)<<17}
__global__ __launch_bounds__(256) void k_binscatter(const void* __restrict__ ei,
                                                    const float* __restrict__ w,
                                                    u32* __restrict__ bcnt,
                                                    uint2* __restrict__ bkt,
                                                    const u32* __restrict__ flag) {
    int e = blockIdx.x * 256 + threadIdx.x;
    if (e >= NE) return;
    u32 is64 = *flag;
    int s, d;
    load_edge(ei, is64, e, s, d);
    int bucket = d >> 7;
    int shard = blockIdx.x & (NSH - 1);
    int sb = shard * NB + bucket;
    u32 pos = atomicAdd(&bcnt[(size_t)sb * CPAD], 1u);   // private 64B line per counter
    if (pos < SUBCAP)
        bkt[(size_t)sb * SUBCAP + pos] =
            make_uint2(__float_as_uint(w[e]), (u32)s | ((u32)(d & 127) << 17));
}

// ---------------- build pass 2: bucket lists -> ELL rows + dinv + cnt ----------------
__global__ __launch_bounds__(256) void k_build(const uint2* __restrict__ bkt,
                                               const u32* __restrict__ bcnt,
                                               uint2* __restrict__ ell,
                                               float* __restrict__ dinv,
                                               u32* __restrict__ cnt) {
    __shared__ u32 lcnt[128];
    __shared__ float lws[128];
    int bucket = blockIdx.x;
    int tid = threadIdx.x;
    if (tid < 128) { lcnt[tid] = 0u; lws[tid] = 0.f; }
    __syncthreads();
    int node0 = bucket << 7;
#pragma unroll 1
    for (int sh = 0; sh < NSH; ++sh) {
        int sb = sh * NB + bucket;
        u32 n = min(bcnt[(size_t)sb * CPAD], (u32)SUBCAP);
        const uint2* lst = bkt + (size_t)sb * SUBCAP;
        for (u32 i = tid; i < n; i += 256) {
            uint2 rec = lst[i];
            u32 src = rec.y & 0x1FFFFu;
            u32 dlo = (rec.y >> 17) & 127u;
            float wv = __uint_as_float(rec.x);
            u32 pos = atomicAdd(&lcnt[dlo], 1u);
            atomicAdd(&lws[dlo], wv);
            if (pos < CAP)
                ell[(size_t)(node0 + dlo) * CAP + pos] = make_uint2(rec.x, src);
        }
    }
    __syncthreads();
    if (tid < 128) {
        int node = node0 + tid;
        if (node < NV) {
            dinv[node] = rsqrtf(1.0f + lws[tid]);
            cnt[node] = min(lcnt[tid], (u32)CAP);
        }
    }
}

// ---------------- GEMM: Y[NV x 128] = dinv[row] * (X @ W), fp16 output ----------------
__device__ inline uint4 pack8h(float4 a, float4 b) {
    __half2 h0 = __float22half2_rn(make_float2(a.x, a.y));
    __half2 h1 = __float22half2_rn(make_float2(a.z, a.w));
    __half2 h2 = __float22half2_rn(make_float2(b.x, b.y));
    __half2 h3 = __float22half2_rn(make_float2(b.z, b.w));
    uint4 r;
    r.x = *(u32*)&h0; r.y = *(u32*)&h1; r.z = *(u32*)&h2; r.w = *(u32*)&h3;
    return r;
}

__device__ inline float4 scale4(float4 a, float s) {
    return make_float4(a.x * s, a.y * s, a.z * s, a.w * s);
}

__global__ __launch_bounds__(256) void k_gemm(const float* __restrict__ X,
                                              const float* __restrict__ Wm,
                                              const float* __restrict__ dinv,
                                              __half* __restrict__ Y) {
    __shared__ float Ws[64 * 128];   // 32 KB (half of W at a time)
    __shared__ float Xs[32 * 132];   // padded stride to dodge bank conflicts
    int tid = threadIdx.x;
    int row0 = blockIdx.x * 32;

    const float4* Xv = (const float4*)(X + (size_t)row0 * NF);
#pragma unroll
    for (int i = 0; i < 4; ++i) {
        int idx = tid + i * 256;
        int r = idx >> 5, c4 = idx & 31;
        *((float4*)(Xs + r * 132) + c4) = Xv[idx];
    }

    int cg = tid & 15, rg = tid >> 4;
    int c0 = cg * 8, r0 = rg * 2;
    float4 a00 = {0, 0, 0, 0}, a01 = {0, 0, 0, 0}, a10 = {0, 0, 0, 0}, a11 = {0, 0, 0, 0};

    for (int half_ = 0; half_ < 2; ++half_) {
        const float4* Wv = (const float4*)(Wm + half_ * 64 * NF);
        __syncthreads();
#pragma unroll
        for (int i = 0; i < 8; ++i) ((float4*)Ws)[tid + i * 256] = Wv[tid + i * 256];
        __syncthreads();
        const float* xr0 = Xs + r0 * 132 + half_ * 64;
        const float* xr1 = xr0 + 132;
#pragma unroll 8
        for (int k = 0; k < 64; ++k) {
            float x0 = xr0[k], x1 = xr1[k];
            float4 w0 = *(const float4*)&Ws[k * 128 + c0];
            float4 w1 = *(const float4*)&Ws[k * 128 + c0 + 4];
            a00.x = fmaf(x0, w0.x, a00.x); a00.y = fmaf(x0, w0.y, a00.y);
            a00.z = fmaf(x0, w0.z, a00.z); a00.w = fmaf(x0, w0.w, a00.w);
            a01.x = fmaf(x0, w1.x, a01.x); a01.y = fmaf(x0, w1.y, a01.y);
            a01.z = fmaf(x0, w1.z, a01.z); a01.w = fmaf(x0, w1.w, a01.w);
            a10.x = fmaf(x1, w0.x, a10.x); a10.y = fmaf(x1, w0.y, a10.y);
            a10.z = fmaf(x1, w0.z, a10.z); a10.w = fmaf(x1, w0.w, a10.w);
            a11.x = fmaf(x1, w1.x, a11.x); a11.y = fmaf(x1, w1.y, a11.y);
            a11.z = fmaf(x1, w1.z, a11.z); a11.w = fmaf(x1, w1.w, a11.w);
        }
    }

    float d0 = dinv[row0 + r0], d1 = dinv[row0 + r0 + 1];
    __half* yr0 = Y + (size_t)(row0 + r0) * NF + c0;
    *(uint4*)yr0 = pack8h(scale4(a00, d0), scale4(a01, d0));
    __half* yr1 = yr0 + NF;
    *(uint4*)yr1 = pack8h(scale4(a10, d1), scale4(a11, d1));
}

// ---------------- aggregation (1 wave per node), fp16 gathers, fused ReLU+LN ----------------
// out[d] = dinv[d] * (xw'[d] + sum_e w_e * xw'[src_e]) + bias,  xw' = dinv*(X@W)
template <int LN>
__global__ __launch_bounds__(256) void k_agg(const __half* __restrict__ xwh,
                                             const uint2* __restrict__ ell,
                                             const u32* __restrict__ cnt,
                                             const float* __restrict__ dinv,
                                             const float* __restrict__ bias,
                                             const float* __restrict__ gamma,
                                             const float* __restrict__ beta,
                                             float* __restrict__ out) {
    int node = blockIdx.x * 4 + (threadIdx.x >> 6);
    int lane = threadIdx.x & 63;
    const u32* xwu = (const u32*)xwh;   // one u32 = 2 fp16 features per lane

    float di = dinv[node];
    u32 sv = xwu[(size_t)node * (NF / 2) + lane];
    float2 xv = __half22float2(*(const __half2*)&sv);
    float ax = xv.x, ay = xv.y;         // self term: xw'[node] (has dinv already)

    const uint2* row = ell + (size_t)node * CAP;
    u32 c = min(cnt[node], (u32)CAP);
    u32 p = 0;
    for (; p + 4 <= c; p += 4) {
        uint2 e0 = row[p], e1 = row[p + 1], e2 = row[p + 2], e3 = row[p + 3];
        u32 s0 = __builtin_amdgcn_readfirstlane(e0.y);
        u32 s1 = __builtin_amdgcn_readfirstlane(e1.y);
        u32 s2 = __builtin_amdgcn_readfirstlane(e2.y);
        u32 s3 = __builtin_amdgcn_readfirstlane(e3.y);
        u32 v0 = xwu[(size_t)s0 * (NF / 2) + lane];
        u32 v1 = xwu[(size_t)s1 * (NF / 2) + lane];
        u32 v2 = xwu[(size_t)s2 * (NF / 2) + lane];
        u32 v3 = xwu[(size_t)s3 * (NF / 2) + lane];
        float c0 = __uint_as_float(e0.x), c1 = __uint_as_float(e1.x);
        float c2 = __uint_as_float(e2.x), c3 = __uint_as_float(e3.x);
        float2 f0 = __half22float2(*(const __half2*)&v0);
        float2 f1 = __half22float2(*(const __half2*)&v1);
        float2 f2 = __half22float2(*(const __half2*)&v2);
        float2 f3 = __half22float2(*(const __half2*)&v3);
        ax = fmaf(c0, f0.x, ax); ay = fmaf(c0, f0.y, ay);
        ax = fmaf(c1, f1.x, ax); ay = fmaf(c1, f1.y, ay);
        ax = fmaf(c2, f2.x, ax); ay = fmaf(c2, f2.y, ay);
        ax = fmaf(c3, f3.x, ax); ay = fmaf(c3, f3.y, ay);
    }
    for (; p < c; ++p) {
        uint2 e0 = row[p];
        u32 s0 = __builtin_amdgcn_readfirstlane(e0.y);
        u32 v0 = xwu[(size_t)s0 * (NF / 2) + lane];
        float2 f0 = __half22float2(*(const __half2*)&v0);
        float cc = __uint_as_float(e0.x);
        ax = fmaf(cc, f0.x, ax); ay = fmaf(cc, f0.y, ay);
    }
    ax = fmaf(ax, di, bias[2 * lane]);
    ay = fmaf(ay, di, bias[2 * lane + 1]);
    if (LN) {
        ax = fmaxf(ax, 0.f); ay = fmaxf(ay, 0.f);
        float s1 = ax + ay, s2 = ax * ax + ay * ay;
#pragma unroll
        for (int o = 32; o > 0; o >>= 1) {
            s1 += __shfl_xor(s1, o);
            s2 += __shfl_xor(s2, o);
        }
        float mu = s1 * (1.f / 128.f);
        float var = fmaf(-mu, mu, s2 * (1.f / 128.f));
        float rstd = rsqrtf(var + 1e-5f);
        ax = fmaf((ax - mu) * rstd, gamma[2 * lane], beta[2 * lane]);
        ay = fmaf((ay - mu) * rstd, gamma[2 * lane + 1], beta[2 * lane + 1]);
    }
    ((float2*)(out + (size_t)node * NF))[lane] = make_float2(ax, ay);
}

// ---------------- launch ----------------
extern "C" void kernel_launch(void* const* d_in, const int* in_sizes, int n_in,
                              void* d_out, int out_size, void* d_ws, size_t ws_size,
                              hipStream_t stream) {
    const float* x  = (const float*)d_in[0];
    const float* ew = (const float*)d_in[1];
    const float* W1 = (const float*)d_in[2];
    const float* b1 = (const float*)d_in[3];
    const float* g1 = (const float*)d_in[4];
    const float* be1 = (const float*)d_in[5];
    const float* W2 = (const float*)d_in[6];
    const float* b2 = (const float*)d_in[7];
    const void*  ei = d_in[8];

    char* ws = (char*)d_ws;
    uint2*  bkt  = (uint2*)(ws + OFF_BKT);
    uint2*  ell  = (uint2*)(ws + OFF_ELL);
    float*  dinv = (float*)(ws + OFF_DINV);
    u32*    bcnt = (u32*)(ws + OFF_BCNT);
    u32*    flag = (u32*)(ws + OFF_FLAG);
    u32*    cnt  = (u32*)(ws + OFF_CNT);
    __half* xwh  = (__half*)(ws + OFF_BKT);   // aliases bucket region (dead after k_build)
    float*  out  = (float*)d_out;
    float*  h    = (float*)d_out;             // layer-1 activations live in d_out

    const int gE = (NE + 255) / 256;          // 12500
    const int gN4 = NV / 4;                   // 25000

    k_detect<<<1, 64, 0, stream>>>((const u32*)ei, flag);
    k_init<<<(NB * NSH + 255) / 256, 256, 0, stream>>>(bcnt);
    k_binscatter<<<gE, 256, 0, stream>>>(ei, ew, bcnt, bkt, flag);
    k_build<<<NB, 256, 0, stream>>>(bkt, bcnt, ell, dinv, cnt);

    k_gemm<<<NV / 32, 256, 0, stream>>>(x, W1, dinv, xwh);
    k_agg<1><<<gN4, 256, 0, stream>>>(xwh, ell, cnt, dinv, b1, g1, be1, h);
    k_gemm<<<NV / 32, 256, 0, stream>>>(h, W2, dinv, xwh);
    k_agg<0><<<gN4, 256, 0, stream>>>(xwh, ell, cnt, dinv, b2, nullptr, nullptr, out);
}

// Round 7
// 485.764 us; speedup vs baseline: 1.2605x; 1.1439x over previous
//
#include <hip/hip_runtime.h>
#include <hip/hip_fp16.h>
#include <stdint.h>

#define NV 100000
#define NE 3200000
#define NF 128
#define CAP 96        // ELL row capacity (exact in-degree Poisson(32); P(>96) ~ 0)
#define NB 782        // bins = ceil(NV/128), 128 nodes per bin
#define NBLK 512      // partition blocks; NE/NBLK = 6250 exact
#define CHUNK 6250

typedef unsigned int u32;

// ---------------- workspace layout (bytes) ----------------
// part : NE uint2            @ 0           (25,600,000)  [xwh fp16 aliases @0 after build]
// ell  : NV*CAP uint2        @ 25600000    (76,800,000)
// hist : NBLK*NB u32         @ 102400000   (1,601,536)
// base : (NB+1) u32          @ 104001536   (3,132)
// dinv : NV f32              @ 104004668 -> align 104004672 (400,000)
// cnt  : NV u32              @ 104404672   (400,000)
// flag : u32                 @ 104804672
// total ~ 104.8 MB
#define OFF_PART  0ull
#define OFF_ELL   25600000ull
#define OFF_HIST  102400000ull
#define OFF_BASE  104001536ull
#define OFF_DINV  104004672ull
#define OFF_CNT   104404672ull
#define OFF_FLAG  104804672ull

// ---------------- edge-index dtype detection ----------------
// int64 indices < 100000 => every odd u32 word is 0.
__global__ void k_detect(const u32* __restrict__ ei_raw, u32* __restrict__ flag) {
    int t = threadIdx.x;  // 64 threads
    unsigned long long ball = __ballot(ei_raw[2 * t + 1] == 0u);
    if (t == 0) *flag = (__popcll(ball) > 32) ? 1u : 0u;
}

__device__ inline int load_dst(const void* ei, u32 is64, int e) {
    return is64 ? (int)((const long long*)ei)[NE + e] : ((const int*)ei)[NE + e];
}
__device__ inline void load_edge(const void* ei, u32 is64, int e, int& s, int& d) {
    if (is64) {
        const long long* p = (const long long*)ei;
        s = (int)p[e];
        d = (int)p[NE + e];
    } else {
        const int* p = (const int*)ei;
        s = p[e];
        d = p[NE + e];
    }
}

// ---------------- pass 1: per-block LDS histogram over dst bins ----------------
__global__ __launch_bounds__(256) void k_hist(const void* __restrict__ ei,
                                              u32* __restrict__ hist,
                                              const u32* __restrict__ flag) {
    __shared__ u32 lh[NB];
    int tid = threadIdx.x, blk = blockIdx.x;
    for (int b = tid; b < NB; b += 256) lh[b] = 0u;
    __syncthreads();
    u32 is64 = *flag;
    int start = blk * CHUNK;
    for (int i = tid; i < CHUNK; i += 256) {
        int d = load_dst(ei, is64, start + i);
        atomicAdd(&lh[d >> 7], 1u);
    }
    __syncthreads();
    for (int b = tid; b < NB; b += 256) hist[(size_t)blk * NB + b] = lh[b];
}

// ---------------- pass 2a: per-bin exclusive scan over blocks (in-place) ----------------
__global__ __launch_bounds__(256) void k_scanA(u32* __restrict__ hist,
                                               u32* __restrict__ tot) {
    __shared__ u32 s[2][NBLK];
    int bin = blockIdx.x, t = threadIdx.x;
    u32 v0 = hist[(size_t)t * NB + bin];
    u32 v1 = hist[(size_t)(t + 256) * NB + bin];
    s[0][t] = v0; s[0][t + 256] = v1;
    __syncthreads();
    int src = 0;
    for (int off = 1; off < NBLK; off <<= 1) {
        int dst = src ^ 1;
        u32 a = s[src][t];       if (t >= off) a += s[src][t - off];
        u32 b = s[src][t + 256]; if (t + 256 >= off) b += s[src][t + 256 - off];
        s[dst][t] = a; s[dst][t + 256] = b;
        __syncthreads();
        src = dst;
    }
    hist[(size_t)t * NB + bin] = s[src][t] - v0;
    hist[(size_t)(t + 256) * NB + bin] = s[src][t + 256] - v1;
    if (t == 0) tot[bin] = s[src][NBLK - 1];
}

// ---------------- pass 2b: scan bin totals -> base offsets ----------------
__global__ __launch_bounds__(256) void k_scanB(const u32* __restrict__ tot,
                                               u32* __restrict__ base) {
    __shared__ u32 ls[2][256];
    int t = threadIdx.x;
    u32 a[4]; u32 sum = 0;
#pragma unroll
    for (int k = 0; k < 4; ++k) {
        int i = t * 4 + k;
        a[k] = (i < NB) ? tot[i] : 0u;
        sum += a[k];
    }
    ls[0][t] = sum;
    __syncthreads();
    int src = 0;
    for (int off = 1; off < 256; off <<= 1) {
        int dst = src ^ 1;
        u32 v = ls[src][t]; if (t >= off) v += ls[src][t - off];
        ls[dst][t] = v;
        __syncthreads();
        src = dst;
    }
    u32 run = ls[src][t] - sum;   // exclusive over threads
#pragma unroll
    for (int k = 0; k < 4; ++k) {
        int i = t * 4 + k;
        if (i < NB) { base[i] = run; run += a[k]; }
    }
    if (t == 255) base[NB] = run;   // == NE
}

// ---------------- pass 3: scatter records to exact positions (no global atomics) ----------------
// record: {w_bits, src | (dst&127)<<17}
__global__ __launch_bounds__(256) void k_part(const void* __restrict__ ei,
                                              const float* __restrict__ w,
                                              const u32* __restrict__ hist,
                                              const u32* __restrict__ base,
                                              uint2* __restrict__ part,
                                              const u32* __restrict__ flag) {
    __shared__ u32 cur[NB];
    int tid = threadIdx.x, blk = blockIdx.x;
    for (int b = tid; b < NB; b += 256)
        cur[b] = base[b] + hist[(size_t)blk * NB + b];
    __syncthreads();
    u32 is64 = *flag;
    int start = blk * CHUNK;
    for (int i = tid; i < CHUNK; i += 256) {
        int e = start + i, s, d;
        load_edge(ei, is64, e, s, d);
        u32 idx = atomicAdd(&cur[d >> 7], 1u);
        part[idx] = make_uint2(__float_as_uint(w[e]), (u32)s | ((u32)(d & 127) << 17));
    }
}

// ---------------- pass 4: bin records -> ELL rows + dinv + cnt ----------------
__global__ __launch_bounds__(256) void k_build(const uint2* __restrict__ part,
                                               const u32* __restrict__ base,
                                               uint2* __restrict__ ell,
                                               float* __restrict__ dinv,
                                               u32* __restrict__ cnt) {
    __shared__ u32 lcnt[128];
    __shared__ float lws[128];
    int bin = blockIdx.x, tid = threadIdx.x;
    if (tid < 128) { lcnt[tid] = 0u; lws[tid] = 0.f; }
    __syncthreads();
    int node0 = bin << 7;
    u32 start = base[bin], end = base[bin + 1];
    for (u32 i = start + tid; i < end; i += 256) {
        uint2 rec = part[i];
        u32 src = rec.y & 0x1FFFFu;
        u32 dlo = (rec.y >> 17) & 127u;
        u32 pos = atomicAdd(&lcnt[dlo], 1u);
        atomicAdd(&lws[dlo], __uint_as_float(rec.x));
        if (pos < CAP)
            ell[(size_t)(node0 + dlo) * CAP + pos] = make_uint2(rec.x, src);
    }
    __syncthreads();
    if (tid < 128) {
        int node = node0 + tid;
        if (node < NV) {
            dinv[node] = rsqrtf(1.0f + lws[tid]);
            cnt[node] = min(lcnt[tid], (u32)CAP);
        }
    }
}

// ---------------- GEMM: Y[NV x 128] = dinv[row] * (X @ W), fp16 output ----------------
__device__ inline uint4 pack8h(float4 a, float4 b) {
    __half2 h0 = __float22half2_rn(make_float2(a.x, a.y));
    __half2 h1 = __float22half2_rn(make_float2(a.z, a.w));
    __half2 h2 = __float22half2_rn(make_float2(b.x, b.y));
    __half2 h3 = __float22half2_rn(make_float2(b.z, b.w));
    uint4 r;
    r.x = *(u32*)&h0; r.y = *(u32*)&h1; r.z = *(u32*)&h2; r.w = *(u32*)&h3;
    return r;
}

__device__ inline float4 scale4(float4 a, float s) {
    return make_float4(a.x * s, a.y * s, a.z * s, a.w * s);
}

__global__ __launch_bounds__(256) void k_gemm(const float* __restrict__ X,
                                              const float* __restrict__ Wm,
                                              const float* __restrict__ dinv,
                                              __half* __restrict__ Y) {
    __shared__ float Ws[64 * 128];   // 32 KB (half of W at a time)
    __shared__ float Xs[32 * 132];   // padded stride to dodge bank conflicts
    int tid = threadIdx.x;
    int row0 = blockIdx.x * 32;

    const float4* Xv = (const float4*)(X + (size_t)row0 * NF);
#pragma unroll
    for (int i = 0; i < 4; ++i) {
        int idx = tid + i * 256;
        int r = idx >> 5, c4 = idx & 31;
        *((float4*)(Xs + r * 132) + c4) = Xv[idx];
    }

    int cg = tid & 15, rg = tid >> 4;
    int c0 = cg * 8, r0 = rg * 2;
    float4 a00 = {0, 0, 0, 0}, a01 = {0, 0, 0, 0}, a10 = {0, 0, 0, 0}, a11 = {0, 0, 0, 0};

    for (int half_ = 0; half_ < 2; ++half_) {
        const float4* Wv = (const float4*)(Wm + half_ * 64 * NF);
        __syncthreads();
#pragma unroll
        for (int i = 0; i < 8; ++i) ((float4*)Ws)[tid + i * 256] = Wv[tid + i * 256];
        __syncthreads();
        const float* xr0 = Xs + r0 * 132 + half_ * 64;
        const float* xr1 = xr0 + 132;
#pragma unroll 8
        for (int k = 0; k < 64; ++k) {
            float x0 = xr0[k], x1 = xr1[k];
            float4 w0 = *(const float4*)&Ws[k * 128 + c0];
            float4 w1 = *(const float4*)&Ws[k * 128 + c0 + 4];
            a00.x = fmaf(x0, w0.x, a00.x); a00.y = fmaf(x0, w0.y, a00.y);
            a00.z = fmaf(x0, w0.z, a00.z); a00.w = fmaf(x0, w0.w, a00.w);
            a01.x = fmaf(x0, w1.x, a01.x); a01.y = fmaf(x0, w1.y, a01.y);
            a01.z = fmaf(x0, w1.z, a01.z); a01.w = fmaf(x0, w1.w, a01.w);
            a10.x = fmaf(x1, w0.x, a10.x); a10.y = fmaf(x1, w0.y, a10.y);
            a10.z = fmaf(x1, w0.z, a10.z); a10.w = fmaf(x1, w0.w, a10.w);
            a11.x = fmaf(x1, w1.x, a11.x); a11.y = fmaf(x1, w1.y, a11.y);
            a11.z = fmaf(x1, w1.z, a11.z); a11.w = fmaf(x1, w1.w, a11.w);
        }
    }

    float d0 = dinv[row0 + r0], d1 = dinv[row0 + r0 + 1];
    __half* yr0 = Y + (size_t)(row0 + r0) * NF + c0;
    *(uint4*)yr0 = pack8h(scale4(a00, d0), scale4(a01, d0));
    __half* yr1 = yr0 + NF;
    *(uint4*)yr1 = pack8h(scale4(a10, d1), scale4(a11, d1));
}

// ---------------- aggregation (1 wave per node), fp16 gathers, fused ReLU+LN ----------------
// out[d] = dinv[d] * (xw'[d] + sum_e w_e * xw'[src_e]) + bias,  xw' = dinv*(X@W)
template <int LN>
__global__ __launch_bounds__(256) void k_agg(const __half* __restrict__ xwh,
                                             const uint2* __restrict__ ell,
                                             const u32* __restrict__ cnt,
                                             const float* __restrict__ dinv,
                                             const float* __restrict__ bias,
                                             const float* __restrict__ gamma,
                                             const float* __restrict__ beta,
                                             float* __restrict__ out) {
    int node = blockIdx.x * 4 + (threadIdx.x >> 6);
    int lane = threadIdx.x & 63;
    const u32* xwu = (const u32*)xwh;   // one u32 = 2 fp16 features per lane

    float di = dinv[node];
    u32 sv = xwu[(size_t)node * (NF / 2) + lane];
    float2 xv = __half22float2(*(const __half2*)&sv);
    float ax = xv.x, ay = xv.y;         // self term: xw'[node] (has dinv already)

    const uint2* row = ell + (size_t)node * CAP;
    u32 c = min(cnt[node], (u32)CAP);
    u32 p = 0;
    for (; p + 4 <= c; p += 4) {
        uint2 e0 = row[p], e1 = row[p + 1], e2 = row[p + 2], e3 = row[p + 3];
        u32 s0 = __builtin_amdgcn_readfirstlane(e0.y);
        u32 s1 = __builtin_amdgcn_readfirstlane(e1.y);
        u32 s2 = __builtin_amdgcn_readfirstlane(e2.y);
        u32 s3 = __builtin_amdgcn_readfirstlane(e3.y);
        u32 v0 = xwu[(size_t)s0 * (NF / 2) + lane];
        u32 v1 = xwu[(size_t)s1 * (NF / 2) + lane];
        u32 v2 = xwu[(size_t)s2 * (NF / 2) + lane];
        u32 v3 = xwu[(size_t)s3 * (NF / 2) + lane];
        float c0 = __uint_as_float(e0.x), c1 = __uint_as_float(e1.x);
        float c2 = __uint_as_float(e2.x), c3 = __uint_as_float(e3.x);
        float2 f0 = __half22float2(*(const __half2*)&v0);
        float2 f1 = __half22float2(*(const __half2*)&v1);
        float2 f2 = __half22float2(*(const __half2*)&v2);
        float2 f3 = __half22float2(*(const __half2*)&v3);
        ax = fmaf(c0, f0.x, ax); ay = fmaf(c0, f0.y, ay);
        ax = fmaf(c1, f1.x, ax); ay = fmaf(c1, f1.y, ay);
        ax = fmaf(c2, f2.x, ax); ay = fmaf(c2, f2.y, ay);
        ax = fmaf(c3, f3.x, ax); ay = fmaf(c3, f3.y, ay);
    }
    for (; p < c; ++p) {
        uint2 e0 = row[p];
        u32 s0 = __builtin_amdgcn_readfirstlane(e0.y);
        u32 v0 = xwu[(size_t)s0 * (NF / 2) + lane];
        float2 f0 = __half22float2(*(const __half2*)&v0);
        float cc = __uint_as_float(e0.x);
        ax = fmaf(cc, f0.x, ax); ay = fmaf(cc, f0.y, ay);
    }
    ax = fmaf(ax, di, bias[2 * lane]);
    ay = fmaf(ay, di, bias[2 * lane + 1]);
    if (LN) {
        ax = fmaxf(ax, 0.f); ay = fmaxf(ay, 0.f);
        float s1 = ax + ay, s2 = ax * ax + ay * ay;
#pragma unroll
        for (int o = 32; o > 0; o >>= 1) {
            s1 += __shfl_xor(s1, o);
            s2 += __shfl_xor(s2, o);
        }
        float mu = s1 * (1.f / 128.f);
        float var = fmaf(-mu, mu, s2 * (1.f / 128.f));
        float rstd = rsqrtf(var + 1e-5f);
        ax = fmaf((ax - mu) * rstd, gamma[2 * lane], beta[2 * lane]);
        ay = fmaf((ay - mu) * rstd, gamma[2 * lane + 1], beta[2 * lane + 1]);
    }
    ((float2*)(out + (size_t)node * NF))[lane] = make_float2(ax, ay);
}

// ---------------- launch ----------------
extern "C" void kernel_launch(void* const* d_in, const int* in_sizes, int n_in,
                              void* d_out, int out_size, void* d_ws, size_t ws_size,
                              hipStream_t stream) {
    const float* x  = (const float*)d_in[0];
    const float* ew = (const float*)d_in[1];
    const float* W1 = (const float*)d_in[2];
    const float* b1 = (const float*)d_in[3];
    const float* g1 = (const float*)d_in[4];
    const float* be1 = (const float*)d_in[5];
    const float* W2 = (const float*)d_in[6];
    const float* b2 = (const float*)d_in[7];
    const void*  ei = d_in[8];

    char* ws = (char*)d_ws;
    uint2*  part = (uint2*)(ws + OFF_PART);
    uint2*  ell  = (uint2*)(ws + OFF_ELL);
    u32*    hist = (u32*)(ws + OFF_HIST);
    u32*    base = (u32*)(ws + OFF_BASE);
    float*  dinv = (float*)(ws + OFF_DINV);
    u32*    cnt  = (u32*)(ws + OFF_CNT);
    u32*    flag = (u32*)(ws + OFF_FLAG);
    u32*    tot  = base + NB + 1;             // reuse tail of base page? no: place after
    // tot needs NB u32; carve from hist tail is unsafe (in use). Use dinv page? No.
    // Simplest: tot lives right after flag.
    tot = (u32*)(ws + OFF_FLAG + 64);
    __half* xwh  = (__half*)(ws + OFF_PART);  // aliases part (dead after k_build)
    float*  out  = (float*)d_out;
    float*  h    = (float*)d_out;             // layer-1 activations live in d_out

    const int gN4 = NV / 4;                   // 25000

    k_detect<<<1, 64, 0, stream>>>((const u32*)ei, flag);
    k_hist<<<NBLK, 256, 0, stream>>>(ei, hist, flag);
    k_scanA<<<NB, 256, 0, stream>>>(hist, tot);
    k_scanB<<<1, 256, 0, stream>>>(tot, base);
    k_part<<<NBLK, 256, 0, stream>>>(ei, ew, hist, base, part, flag);
    k_build<<<NB, 256, 0, stream>>>(part, base, ell, dinv, cnt);

    k_gemm<<<NV / 32, 256, 0, stream>>>(x, W1, dinv, xwh);
    k_agg<1><<<gN4, 256, 0, stream>>>(xwh, ell, cnt, dinv, b1, g1, be1, h);
    k_gemm<<<NV / 32, 256, 0, stream>>>(h, W2, dinv, xwh);
    k_agg<0><<<gN4, 256, 0, stream>>>(xwh, ell, cnt, dinv, b2, nullptr, nullptr, out);
}

// Round 8
// 448.450 us; speedup vs baseline: 1.3653x; 1.0832x over previous
//
#include <hip/hip_runtime.h>
#include <hip/hip_fp16.h>
#include <stdint.h>

#define NV 100000
#define NE 3200000
#define NF 128
#define CAP 96        // ELL row capacity (exact in-degree Poisson(32); P(>96) ~ 0)
#define NB 782        // bins = ceil(NV/128), 128 nodes per bin
#define NBLK 512      // partition blocks; NE/NBLK = 6250 exact
#define CHUNK 6250

typedef unsigned int u32;

// ---------------- workspace layout (bytes) ----------------
// part : NE uint2            @ 0           (25,600,000)  [xwh fp16 aliases @0 after build]
// ell  : NV*CAP uint2        @ 25600000    (76,800,000)
// hist : NBLK*NB u32         @ 102400000   (1,601,536)
// base : (NB+1) u32          @ 104001536   (3,132)
// dinv : NV f32              @ 104004672   (400,000)
// cnt  : NV u32              @ 104404672   (400,000)
// flag : u32                 @ 104804672
// tot  : NB u32              @ 104804736
// total ~ 104.8 MB
#define OFF_PART  0ull
#define OFF_ELL   25600000ull
#define OFF_HIST  102400000ull
#define OFF_BASE  104001536ull
#define OFF_DINV  104004672ull
#define OFF_CNT   104404672ull
#define OFF_FLAG  104804672ull

// ---------------- edge-index dtype detection ----------------
// int64 indices < 100000 => every odd u32 word is 0.
__global__ void k_detect(const u32* __restrict__ ei_raw, u32* __restrict__ flag) {
    int t = threadIdx.x;  // 64 threads
    unsigned long long ball = __ballot(ei_raw[2 * t + 1] == 0u);
    if (t == 0) *flag = (__popcll(ball) > 32) ? 1u : 0u;
}

__device__ inline int load_dst(const void* ei, u32 is64, int e) {
    return is64 ? (int)((const long long*)ei)[NE + e] : ((const int*)ei)[NE + e];
}
__device__ inline void load_edge(const void* ei, u32 is64, int e, int& s, int& d) {
    if (is64) {
        const long long* p = (const long long*)ei;
        s = (int)p[e];
        d = (int)p[NE + e];
    } else {
        const int* p = (const int*)ei;
        s = p[e];
        d = p[NE + e];
    }
}

// ---------------- pass 1: per-block LDS histogram over dst bins ----------------
__global__ __launch_bounds__(256) void k_hist(const void* __restrict__ ei,
                                              u32* __restrict__ hist,
                                              const u32* __restrict__ flag) {
    __shared__ u32 lh[NB];
    int tid = threadIdx.x, blk = blockIdx.x;
    for (int b = tid; b < NB; b += 256) lh[b] = 0u;
    __syncthreads();
    u32 is64 = *flag;
    int start = blk * CHUNK;
    for (int i = tid; i < CHUNK; i += 256) {
        int d = load_dst(ei, is64, start + i);
        atomicAdd(&lh[d >> 7], 1u);
    }
    __syncthreads();
    for (int b = tid; b < NB; b += 256) hist[(size_t)blk * NB + b] = lh[b];
}

// ---------------- pass 2a: per-bin exclusive scan over blocks (in-place) ----------------
__global__ __launch_bounds__(256) void k_scanA(u32* __restrict__ hist,
                                               u32* __restrict__ tot) {
    __shared__ u32 s[2][NBLK];
    int bin = blockIdx.x, t = threadIdx.x;
    u32 v0 = hist[(size_t)t * NB + bin];
    u32 v1 = hist[(size_t)(t + 256) * NB + bin];
    s[0][t] = v0; s[0][t + 256] = v1;
    __syncthreads();
    int src = 0;
    for (int off = 1; off < NBLK; off <<= 1) {
        int dst = src ^ 1;
        u32 a = s[src][t];       if (t >= off) a += s[src][t - off];
        u32 b = s[src][t + 256]; if (t + 256 >= off) b += s[src][t + 256 - off];
        s[dst][t] = a; s[dst][t + 256] = b;
        __syncthreads();
        src = dst;
    }
    hist[(size_t)t * NB + bin] = s[src][t] - v0;
    hist[(size_t)(t + 256) * NB + bin] = s[src][t + 256] - v1;
    if (t == 0) tot[bin] = s[src][NBLK - 1];
}

// ---------------- pass 2b: scan bin totals -> base offsets ----------------
__global__ __launch_bounds__(256) void k_scanB(const u32* __restrict__ tot,
                                               u32* __restrict__ base) {
    __shared__ u32 ls[2][256];
    int t = threadIdx.x;
    u32 a[4]; u32 sum = 0;
#pragma unroll
    for (int k = 0; k < 4; ++k) {
        int i = t * 4 + k;
        a[k] = (i < NB) ? tot[i] : 0u;
        sum += a[k];
    }
    ls[0][t] = sum;
    __syncthreads();
    int src = 0;
    for (int off = 1; off < 256; off <<= 1) {
        int dst = src ^ 1;
        u32 v = ls[src][t]; if (t >= off) v += ls[src][t - off];
        ls[dst][t] = v;
        __syncthreads();
        src = dst;
    }
    u32 run = ls[src][t] - sum;   // exclusive over threads
#pragma unroll
    for (int k = 0; k < 4; ++k) {
        int i = t * 4 + k;
        if (i < NB) { base[i] = run; run += a[k]; }
    }
    if (t == 255) base[NB] = run;   // == NE
}

// ---------------- pass 3: scatter records to exact positions (no global atomics) ----------------
// record: {w_bits, src | (dst&127)<<17}
__global__ __launch_bounds__(256) void k_part(const void* __restrict__ ei,
                                              const float* __restrict__ w,
                                              const u32* __restrict__ hist,
                                              const u32* __restrict__ base,
                                              uint2* __restrict__ part,
                                              const u32* __restrict__ flag) {
    __shared__ u32 cur[NB];
    int tid = threadIdx.x, blk = blockIdx.x;
    for (int b = tid; b < NB; b += 256)
        cur[b] = base[b] + hist[(size_t)blk * NB + b];
    __syncthreads();
    u32 is64 = *flag;
    int start = blk * CHUNK;
    for (int i = tid; i < CHUNK; i += 256) {
        int e = start + i, s, d;
        load_edge(ei, is64, e, s, d);
        u32 idx = atomicAdd(&cur[d >> 7], 1u);
        part[idx] = make_uint2(__float_as_uint(w[e]), (u32)s | ((u32)(d & 127) << 17));
    }
}

// ---------------- pass 4: bin records -> ELL rows + dinv + cnt ----------------
__global__ __launch_bounds__(256) void k_build(const uint2* __restrict__ part,
                                               const u32* __restrict__ base,
                                               uint2* __restrict__ ell,
                                               float* __restrict__ dinv,
                                               u32* __restrict__ cnt) {
    __shared__ u32 lcnt[128];
    __shared__ float lws[128];
    int bin = blockIdx.x, tid = threadIdx.x;
    if (tid < 128) { lcnt[tid] = 0u; lws[tid] = 0.f; }
    __syncthreads();
    int node0 = bin << 7;
    u32 start = base[bin], end = base[bin + 1];
    for (u32 i = start + tid; i < end; i += 256) {
        uint2 rec = part[i];
        u32 src = rec.y & 0x1FFFFu;
        u32 dlo = (rec.y >> 17) & 127u;
        u32 pos = atomicAdd(&lcnt[dlo], 1u);
        atomicAdd(&lws[dlo], __uint_as_float(rec.x));
        if (pos < CAP)
            ell[(size_t)(node0 + dlo) * CAP + pos] = make_uint2(rec.x, src);
    }
    __syncthreads();
    if (tid < 128) {
        int node = node0 + tid;
        if (node < NV) {
            dinv[node] = rsqrtf(1.0f + lws[tid]);
            cnt[node] = min(lcnt[tid], (u32)CAP);
        }
    }
}

// ---------------- GEMM: Y[NV x 128] = dinv[row] * (X @ W), fp16 output ----------------
__device__ inline uint4 pack8h(float4 a, float4 b) {
    __half2 h0 = __float22half2_rn(make_float2(a.x, a.y));
    __half2 h1 = __float22half2_rn(make_float2(a.z, a.w));
    __half2 h2 = __float22half2_rn(make_float2(b.x, b.y));
    __half2 h3 = __float22half2_rn(make_float2(b.z, b.w));
    uint4 r;
    r.x = *(u32*)&h0; r.y = *(u32*)&h1; r.z = *(u32*)&h2; r.w = *(u32*)&h3;
    return r;
}

__device__ inline float4 scale4(float4 a, float s) {
    return make_float4(a.x * s, a.y * s, a.z * s, a.w * s);
}

__global__ __launch_bounds__(256) void k_gemm(const float* __restrict__ X,
                                              const float* __restrict__ Wm,
                                              const float* __restrict__ dinv,
                                              __half* __restrict__ Y) {
    __shared__ float Ws[64 * 128];   // 32 KB (half of W at a time)
    __shared__ float Xs[32 * 132];   // padded stride to dodge bank conflicts
    int tid = threadIdx.x;
    int row0 = blockIdx.x * 32;

    const float4* Xv = (const float4*)(X + (size_t)row0 * NF);
#pragma unroll
    for (int i = 0; i < 4; ++i) {
        int idx = tid + i * 256;
        int r = idx >> 5, c4 = idx & 31;
        *((float4*)(Xs + r * 132) + c4) = Xv[idx];
    }

    int cg = tid & 15, rg = tid >> 4;
    int c0 = cg * 8, r0 = rg * 2;
    float4 a00 = {0, 0, 0, 0}, a01 = {0, 0, 0, 0}, a10 = {0, 0, 0, 0}, a11 = {0, 0, 0, 0};

    for (int half_ = 0; half_ < 2; ++half_) {
        const float4* Wv = (const float4*)(Wm + half_ * 64 * NF);
        __syncthreads();
#pragma unroll
        for (int i = 0; i < 8; ++i) ((float4*)Ws)[tid + i * 256] = Wv[tid + i * 256];
        __syncthreads();
        const float* xr0 = Xs + r0 * 132 + half_ * 64;
        const float* xr1 = xr0 + 132;
#pragma unroll 8
        for (int k = 0; k < 64; ++k) {
            float x0 = xr0[k], x1 = xr1[k];
            float4 w0 = *(const float4*)&Ws[k * 128 + c0];
            float4 w1 = *(const float4*)&Ws[k * 128 + c0 + 4];
            a00.x = fmaf(x0, w0.x, a00.x); a00.y = fmaf(x0, w0.y, a00.y);
            a00.z = fmaf(x0, w0.z, a00.z); a00.w = fmaf(x0, w0.w, a00.w);
            a01.x = fmaf(x0, w1.x, a01.x); a01.y = fmaf(x0, w1.y, a01.y);
            a01.z = fmaf(x0, w1.z, a01.z); a01.w = fmaf(x0, w1.w, a01.w);
            a10.x = fmaf(x1, w0.x, a10.x); a10.y = fmaf(x1, w0.y, a10.y);
            a10.z = fmaf(x1, w0.z, a10.z); a10.w = fmaf(x1, w0.w, a10.w);
            a11.x = fmaf(x1, w1.x, a11.x); a11.y = fmaf(x1, w1.y, a11.y);
            a11.z = fmaf(x1, w1.z, a11.z); a11.w = fmaf(x1, w1.w, a11.w);
        }
    }

    float d0 = dinv[row0 + r0], d1 = dinv[row0 + r0 + 1];
    __half* yr0 = Y + (size_t)(row0 + r0) * NF + c0;
    *(uint4*)yr0 = pack8h(scale4(a00, d0), scale4(a01, d0));
    __half* yr1 = yr0 + NF;
    *(uint4*)yr1 = pack8h(scale4(a10, d1), scale4(a11, d1));
}

// ---------------- aggregation: wave per node, WIDE gathers ----------------
// lane = (replica g = lane>>4) x (chunk ch = lane&15); one uint4 gather = 8 fp16
// features of one edge's src row; 4 edges per gather instruction; 16 edges/iter.
// out[d] = dinv[d]*(xw'[d] + sum_e w_e*xw'[src_e]) + bias, xw' = dinv*(X@W)
#define ACC8(g, cf)                                                         \
    {                                                                       \
        float2 f_;                                                          \
        f_ = __half22float2(*(const __half2*)&(g).x);                       \
        a0 = fmaf(cf, f_.x, a0); a1 = fmaf(cf, f_.y, a1);                   \
        f_ = __half22float2(*(const __half2*)&(g).y);                       \
        a2 = fmaf(cf, f_.x, a2); a3 = fmaf(cf, f_.y, a3);                   \
        f_ = __half22float2(*(const __half2*)&(g).z);                       \
        a4 = fmaf(cf, f_.x, a4); a5 = fmaf(cf, f_.y, a5);                   \
        f_ = __half22float2(*(const __half2*)&(g).w);                       \
        a6 = fmaf(cf, f_.x, a6); a7 = fmaf(cf, f_.y, a7);                   \
    }

template <int LN>
__global__ __launch_bounds__(256) void k_agg(const __half* __restrict__ xwh,
                                             const uint2* __restrict__ ell,
                                             const u32* __restrict__ cnt,
                                             const float* __restrict__ dinv,
                                             const float* __restrict__ bias,
                                             const float* __restrict__ gamma,
                                             const float* __restrict__ beta,
                                             float* __restrict__ out) {
    int node = blockIdx.x * 4 + (threadIdx.x >> 6);
    int lane = threadIdx.x & 63;
    int grp = lane >> 4;      // replica 0..3 (edge sub-group)
    int ch = lane & 15;       // feature chunk: 8 features
    const uint4* xw4 = (const uint4*)xwh;   // 16B = 8 fp16 features

    float di = dinv[node];
    uint4 sv = xw4[(size_t)node * 16 + ch];   // self chunk (same for all replicas)

    float a0 = 0, a1 = 0, a2 = 0, a3 = 0, a4 = 0, a5 = 0, a6 = 0, a7 = 0;

    const uint2* row = ell + (size_t)node * CAP;
    u32 c = min(cnt[node], (u32)CAP);
    for (u32 p = 0; p < c; p += 16) {
        u32 i0 = p + grp, i1 = p + 4 + grp, i2 = p + 8 + grp, i3 = p + 12 + grp;
        uint2 r0 = row[min(i0, c - 1)];
        uint2 r1 = row[min(i1, c - 1)];
        uint2 r2 = row[min(i2, c - 1)];
        uint2 r3 = row[min(i3, c - 1)];
        uint4 g0 = xw4[(size_t)(r0.y & 0x1FFFFu) * 16 + ch];
        uint4 g1 = xw4[(size_t)(r1.y & 0x1FFFFu) * 16 + ch];
        uint4 g2 = xw4[(size_t)(r2.y & 0x1FFFFu) * 16 + ch];
        uint4 g3 = xw4[(size_t)(r3.y & 0x1FFFFu) * 16 + ch];
        float c0 = (i0 < c) ? __uint_as_float(r0.x) : 0.f;
        float c1 = (i1 < c) ? __uint_as_float(r1.x) : 0.f;
        float c2 = (i2 < c) ? __uint_as_float(r2.x) : 0.f;
        float c3 = (i3 < c) ? __uint_as_float(r3.x) : 0.f;
        ACC8(g0, c0);
        ACC8(g1, c1);
        ACC8(g2, c2);
        ACC8(g3, c3);
    }

    // reduce the 4 replicas (lanes l, l^16, l^32, l^48)
#define RED(a) a += __shfl_xor(a, 16); a += __shfl_xor(a, 32);
    RED(a0) RED(a1) RED(a2) RED(a3) RED(a4) RED(a5) RED(a6) RED(a7)
#undef RED

    // self term (add once, after replica reduction)
    {
        float2 f_;
        f_ = __half22float2(*(const __half2*)&sv.x); a0 += f_.x; a1 += f_.y;
        f_ = __half22float2(*(const __half2*)&sv.y); a2 += f_.x; a3 += f_.y;
        f_ = __half22float2(*(const __half2*)&sv.z); a4 += f_.x; a5 += f_.y;
        f_ = __half22float2(*(const __half2*)&sv.w); a6 += f_.x; a7 += f_.y;
    }

    float4 b0 = *(const float4*)&bias[ch * 8];
    float4 b1 = *(const float4*)&bias[ch * 8 + 4];
    a0 = fmaf(a0, di, b0.x); a1 = fmaf(a1, di, b0.y);
    a2 = fmaf(a2, di, b0.z); a3 = fmaf(a3, di, b0.w);
    a4 = fmaf(a4, di, b1.x); a5 = fmaf(a5, di, b1.y);
    a6 = fmaf(a6, di, b1.z); a7 = fmaf(a7, di, b1.w);

    if (LN) {
        a0 = fmaxf(a0, 0.f); a1 = fmaxf(a1, 0.f); a2 = fmaxf(a2, 0.f);
        a3 = fmaxf(a3, 0.f); a4 = fmaxf(a4, 0.f); a5 = fmaxf(a5, 0.f);
        a6 = fmaxf(a6, 0.f); a7 = fmaxf(a7, 0.f);
        float s1 = a0 + a1 + a2 + a3 + a4 + a5 + a6 + a7;
        float s2 = a0 * a0 + a1 * a1 + a2 * a2 + a3 * a3 +
                   a4 * a4 + a5 * a5 + a6 * a6 + a7 * a7;
#pragma unroll
        for (int o = 8; o > 0; o >>= 1) {   // reduce over the 16-lane chunk group
            s1 += __shfl_xor(s1, o);
            s2 += __shfl_xor(s2, o);
        }
        float mu = s1 * (1.f / 128.f);
        float var = fmaf(-mu, mu, s2 * (1.f / 128.f));
        float rstd = rsqrtf(var + 1e-5f);
        float4 gm0 = *(const float4*)&gamma[ch * 8];
        float4 gm1 = *(const float4*)&gamma[ch * 8 + 4];
        float4 bt0 = *(const float4*)&beta[ch * 8];
        float4 bt1 = *(const float4*)&beta[ch * 8 + 4];
        a0 = fmaf((a0 - mu) * rstd, gm0.x, bt0.x);
        a1 = fmaf((a1 - mu) * rstd, gm0.y, bt0.y);
        a2 = fmaf((a2 - mu) * rstd, gm0.z, bt0.z);
        a3 = fmaf((a3 - mu) * rstd, gm0.w, bt0.w);
        a4 = fmaf((a4 - mu) * rstd, gm1.x, bt1.x);
        a5 = fmaf((a5 - mu) * rstd, gm1.y, bt1.y);
        a6 = fmaf((a6 - mu) * rstd, gm1.z, bt1.z);
        a7 = fmaf((a7 - mu) * rstd, gm1.w, bt1.w);
    }

    if (grp == 0) {
        float* o = out + (size_t)node * NF + ch * 8;
        *(float4*)o = make_float4(a0, a1, a2, a3);
        *(float4*)(o + 4) = make_float4(a4, a5, a6, a7);
    }
}

// ---------------- launch ----------------
extern "C" void kernel_launch(void* const* d_in, const int* in_sizes, int n_in,
                              void* d_out, int out_size, void* d_ws, size_t ws_size,
                              hipStream_t stream) {
    const float* x  = (const float*)d_in[0];
    const float* ew = (const float*)d_in[1];
    const float* W1 = (const float*)d_in[2];
    const float* b1 = (const float*)d_in[3];
    const float* g1 = (const float*)d_in[4];
    const float* be1 = (const float*)d_in[5];
    const float* W2 = (const float*)d_in[6];
    const float* b2 = (const float*)d_in[7];
    const void*  ei = d_in[8];

    char* ws = (char*)d_ws;
    uint2*  part = (uint2*)(ws + OFF_PART);
    uint2*  ell  = (uint2*)(ws + OFF_ELL);
    u32*    hist = (u32*)(ws + OFF_HIST);
    u32*    base = (u32*)(ws + OFF_BASE);
    float*  dinv = (float*)(ws + OFF_DINV);
    u32*    cnt  = (u32*)(ws + OFF_CNT);
    u32*    flag = (u32*)(ws + OFF_FLAG);
    u32*    tot  = (u32*)(ws + OFF_FLAG + 64);
    __half* xwh  = (__half*)(ws + OFF_PART);  // aliases part (dead after k_build)
    float*  out  = (float*)d_out;
    float*  h    = (float*)d_out;             // layer-1 activations live in d_out

    const int gN4 = NV / 4;                   // 25000

    k_detect<<<1, 64, 0, stream>>>((const u32*)ei, flag);
    k_hist<<<NBLK, 256, 0, stream>>>(ei, hist, flag);
    k_scanA<<<NB, 256, 0, stream>>>(hist, tot);
    k_scanB<<<1, 256, 0, stream>>>(tot, base);
    k_part<<<NBLK, 256, 0, stream>>>(ei, ew, hist, base, part, flag);
    k_build<<<NB, 256, 0, stream>>>(part, base, ell, dinv, cnt);

    k_gemm<<<NV / 32, 256, 0, stream>>>(x, W1, dinv, xwh);
    k_agg<1><<<gN4, 256, 0, stream>>>(xwh, ell, cnt, dinv, b1, g1, be1, h);
    k_gemm<<<NV / 32, 256, 0, stream>>>(h, W2, dinv, xwh);
    k_agg<0><<<gN4, 256, 0, stream>>>(xwh, ell, cnt, dinv, b2, nullptr, nullptr, out);
}